// Round 6
// baseline (597.538 us; speedup 1.0000x reference)
//
#include <hip/hip_runtime.h>
#include <hip/hip_bf16.h>
#include <math.h>

// ---------------- problem constants ----------------
#define BATCH 2
#define SEQ   2048
#define DDIM  2048
#define NH    16
#define HD    128
#define MROWS (BATCH * SEQ)   // 4096

typedef unsigned short u16;
typedef __bf16 bf16x8 __attribute__((ext_vector_type(8)));
typedef float  f32x4  __attribute__((ext_vector_type(4)));
typedef float  f32x16 __attribute__((ext_vector_type(16)));

// round-to-nearest-even f32 -> bf16 bits
__device__ __forceinline__ u16 f2bf(float f) {
  unsigned int u = __float_as_uint(f);
  u += 0x7fffu + ((u >> 16) & 1u);
  return (u16)(u >> 16);
}
__device__ __forceinline__ float bf2f(u16 h) {
  return __uint_as_float(((unsigned int)h) << 16);
}

// async global->LDS, 16B per lane; LDS dest is wave-uniform base + lane*16
__device__ __forceinline__ void gload16(const void* g, void* s) {
  __builtin_amdgcn_global_load_lds((const __attribute__((address_space(1))) void*)g,
                                   (__attribute__((address_space(3))) void*)s, 16, 0, 0);
}

// ---------------- X f32 -> (hi, lo) bf16 pair ----------------
__global__ void split_x(const float* __restrict__ in, u16* __restrict__ hi,
                        u16* __restrict__ lo) {
  const int i = blockIdx.x * blockDim.x + threadIdx.x;   // one float4 per thread
  float4 v = ((const float4*)in)[i];
  ushort4 h, l;
  h.x = f2bf(v.x); l.x = f2bf(v.x - bf2f(h.x));
  h.y = f2bf(v.y); l.y = f2bf(v.y - bf2f(h.y));
  h.z = f2bf(v.z); l.z = f2bf(v.z - bf2f(h.z));
  h.w = f2bf(v.w); l.w = f2bf(v.w - bf2f(h.w));
  ((ushort4*)hi)[i] = h;
  ((ushort4*)lo)[i] = l;
}

// ---------------- W [K][N] f32 -> Wt [N][K] bf16 (hi [+ lo]) ----------------
__global__ void transpose_w(const float* __restrict__ W, u16* __restrict__ Wth,
                            u16* __restrict__ Wtl) {
  __shared__ float t[32][33];
  const int tx = threadIdx.x, ty = threadIdx.y;          // 32 x 8
  const int c0 = blockIdx.x * 32, r0 = blockIdx.y * 32;  // c0: n, r0: k
#pragma unroll
  for (int i = 0; i < 4; ++i)
    t[ty + i * 8][tx] = W[(size_t)(r0 + ty + i * 8) * DDIM + c0 + tx];
  __syncthreads();
#pragma unroll
  for (int i = 0; i < 4; ++i) {
    const float v = t[tx][ty + i * 8];
    const u16 h = f2bf(v);
    const size_t idx = (size_t)(c0 + ty + i * 8) * DDIM + r0 + tx;
    Wth[idx] = h;
    if (Wtl) Wtl[idx] = f2bf(v - bf2f(h));
  }
}

// ---------------- V [B*S][D] bf16 -> Vt [B*H][HD][S] bf16 ----------------
__global__ void transpose_v(const u16* __restrict__ V, u16* __restrict__ Vt) {
  __shared__ u16 t[32][33];
  const int tx = threadIdx.x, ty = threadIdx.y;          // 32 x 8
  const int s0 = blockIdx.x * 32;
  const int d0 = blockIdx.y * 32;
  const int bh = blockIdx.z;
  const int b = bh >> 4, h = bh & 15;
#pragma unroll
  for (int i = 0; i < 4; ++i)
    t[ty + i * 8][tx] = V[(size_t)(b * SEQ + s0 + ty + i * 8) * DDIM + h * HD + d0 + tx];
  __syncthreads();
#pragma unroll
  for (int i = 0; i < 4; ++i)
    Vt[((size_t)bh * HD + d0 + ty + i * 8) * SEQ + s0 + tx] = t[tx][ty + i * 8];
}

// ---------------- single-term GEMM: C[M,N] = A[M,K] x Bt[N,K]^T ----------------
template <int MODE>
__global__ __launch_bounds__(256)
void gemm_kernel(const u16* __restrict__ A, const u16* __restrict__ Bt,
                 void* __restrict__ Cout, const float* __restrict__ bias) {
  constexpr int K = DDIM, N = DDIM;
  __shared__ __align__(16) u16 As[128 * 64];
  __shared__ __align__(16) u16 Bs[128 * 64];
  const int tid = threadIdx.x;
  const int wave = tid >> 6;
  const int lane = tid & 63;
  const int lr = lane & 15, lg = lane >> 4;
  const int bm = blockIdx.y * 128, bn = blockIdx.x * 128;
  const int wr = wave >> 1, wc = wave & 1;

  f32x4 acc[4][4] = {};

  const int srow = wave * 32 + (lane >> 3);
  const int scol = (lane & 7) * 8;
  const u16* Ag = A  + (size_t)(bm + srow) * K + scol;
  const u16* Bg = Bt + (size_t)(bn + srow) * K + scol;

  for (int k0 = 0; k0 < K; k0 += 64) {
    __syncthreads();
#pragma unroll
    for (int it = 0; it < 4; ++it) {
      gload16(Ag + (size_t)it * 8 * K + k0, &As[(wave * 32 + it * 8) * 64]);
      gload16(Bg + (size_t)it * 8 * K + k0, &Bs[(wave * 32 + it * 8) * 64]);
    }
    __syncthreads();
#pragma unroll
    for (int kk = 0; kk < 64; kk += 32) {
      bf16x8 af[4], bfr[4];
#pragma unroll
      for (int i = 0; i < 4; ++i)
        af[i] = *(const bf16x8*)&As[(wr * 64 + i * 16 + lr) * 64 + kk + lg * 8];
#pragma unroll
      for (int j = 0; j < 4; ++j)
        bfr[j] = *(const bf16x8*)&Bs[(wc * 64 + j * 16 + lr) * 64 + kk + lg * 8];
#pragma unroll
      for (int i = 0; i < 4; ++i)
#pragma unroll
        for (int j = 0; j < 4; ++j)
          acc[i][j] = __builtin_amdgcn_mfma_f32_16x16x32_bf16(af[i], bfr[j], acc[i][j], 0, 0, 0);
    }
  }

#pragma unroll
  for (int i = 0; i < 4; ++i) {
    const int row0 = bm + wr * 64 + i * 16 + lg * 4;
#pragma unroll
    for (int j = 0; j < 4; ++j) {
      const int col = bn + wc * 64 + j * 16 + lr;
#pragma unroll
      for (int e = 0; e < 4; ++e) {
        const int row = row0 + e;
        const float v = acc[i][j][e];
        if constexpr (MODE == 0) {
          ((u16*)Cout)[(size_t)row * N + col] = f2bf(v);
        } else {
          ((float*)Cout)[(size_t)row * N + col] = v + bias[col];
        }
      }
    }
  }
}

// ------- split GEMM: C = A x (Bh+Bl)^T (+ Al x Bh^T if TERMS==3) -------
template <int TERMS, bool WRITE_LO>
__global__ __launch_bounds__(256)
void gemm3_kernel(const u16* __restrict__ Ah, const u16* __restrict__ Al,
                  const u16* __restrict__ Bh, const u16* __restrict__ Bl,
                  u16* __restrict__ Ch, u16* __restrict__ Cl) {
  constexpr int K = DDIM, N = DDIM;
  __shared__ __align__(16) u16 Ash[128 * 64];
  __shared__ __align__(16) u16 Asl[TERMS == 3 ? 128 * 64 : 8];
  __shared__ __align__(16) u16 Bsh[128 * 64];
  __shared__ __align__(16) u16 Bsl[128 * 64];
  const int tid = threadIdx.x;
  const int wave = tid >> 6;
  const int lane = tid & 63;
  const int lr = lane & 15, lg = lane >> 4;
  const int bm = blockIdx.y * 128, bn = blockIdx.x * 128;
  const int wr = wave >> 1, wc = wave & 1;

  f32x4 acc[4][4] = {};

  const int srow = wave * 32 + (lane >> 3);
  const int scol = (lane & 7) * 8;
  const size_t aoff = (size_t)(bm + srow) * K + scol;
  const size_t boff = (size_t)(bn + srow) * K + scol;

  for (int k0 = 0; k0 < K; k0 += 64) {
    __syncthreads();
#pragma unroll
    for (int it = 0; it < 4; ++it) {
      const size_t ro = (size_t)it * 8 * K + k0;
      const int ls = (wave * 32 + it * 8) * 64;
      gload16(Ah + aoff + ro, &Ash[ls]);
      if constexpr (TERMS == 3) gload16(Al + aoff + ro, &Asl[ls]);
      gload16(Bh + boff + ro, &Bsh[ls]);
      gload16(Bl + boff + ro, &Bsl[ls]);
    }
    __syncthreads();
#pragma unroll
    for (int kk = 0; kk < 64; kk += 32) {
      bf16x8 ah[4], al[4], bh[4], bl[4];
#pragma unroll
      for (int i = 0; i < 4; ++i) {
        const int off = (wr * 64 + i * 16 + lr) * 64 + kk + lg * 8;
        ah[i] = *(const bf16x8*)&Ash[off];
        if constexpr (TERMS == 3) al[i] = *(const bf16x8*)&Asl[off];
      }
#pragma unroll
      for (int j = 0; j < 4; ++j) {
        const int off = (wc * 64 + j * 16 + lr) * 64 + kk + lg * 8;
        bh[j] = *(const bf16x8*)&Bsh[off];
        bl[j] = *(const bf16x8*)&Bsl[off];
      }
#pragma unroll
      for (int i = 0; i < 4; ++i)
#pragma unroll
        for (int j = 0; j < 4; ++j) {
          acc[i][j] = __builtin_amdgcn_mfma_f32_16x16x32_bf16(ah[i], bh[j], acc[i][j], 0, 0, 0);
          acc[i][j] = __builtin_amdgcn_mfma_f32_16x16x32_bf16(ah[i], bl[j], acc[i][j], 0, 0, 0);
          if constexpr (TERMS == 3)
            acc[i][j] = __builtin_amdgcn_mfma_f32_16x16x32_bf16(al[i], bh[j], acc[i][j], 0, 0, 0);
        }
    }
  }

#pragma unroll
  for (int i = 0; i < 4; ++i) {
    const int row0 = bm + wr * 64 + i * 16 + lg * 4;
#pragma unroll
    for (int j = 0; j < 4; ++j) {
      const int col = bn + wc * 64 + j * 16 + lr;
#pragma unroll
      for (int e = 0; e < 4; ++e) {
        const float v = acc[i][j][e];
        const u16 h = f2bf(v);
        const size_t idx = (size_t)(row0 + e) * N + col;
        Ch[idx] = h;
        if constexpr (WRITE_LO) Cl[idx] = f2bf(v - bf2f(h));
      }
    }
  }
}

// ---------------- causal flash attention v4: swapped 32x32 MFMA ----------------
// 512 blocks x 256 threads (4 waves x 32 q-rows = 128 q-rows/block).
// QK^T = mfma_32x32x16(K_frag, Q_frag) -> P cols are lane-local in q (col=lane&31):
// softmax = in-lane reduce + ONE shfl_xor(32). P -> PV B-operand fully in registers
// (bf16 pack + shfl_xor(32)), PV = mfma(Vt_frag, P). No P LDS traffic.
// LPT dispatch: descending qb queue per XCD. KVBLK=64 double-buffered.
__global__ __launch_bounds__(256, 1)
void attn_kernel(const u16* __restrict__ Qh, const u16* __restrict__ Khp,
                 const u16* __restrict__ Klp, const u16* __restrict__ Vt,
                 u16* __restrict__ ctx) {
  __shared__ __align__(16) u16 Ksh[2][64 * 128];   // [key][d]  rows 256B, swz (r&7)<<4
  __shared__ __align__(16) u16 Ksl[2][64 * 128];
  __shared__ __align__(16) u16 Vs [2][128 * 64];   // [d][key]  rows 128B, swz (d&7)<<4
  const int tid = threadIdx.x;
  const int wave = tid >> 6, lane = tid & 63;
  const int lq = lane & 31;        // this lane's q column (within wave's 32 rows)
  const int hi = lane >> 5;        // half-select
  const float NEG_INF = -__builtin_inff();

  // LPT: per-XCD queue runs qb 15..0 (longest first), 4 heads per XCD.
  const int id = blockIdx.x;
  const int xcd = id & 7;
  const int j = id >> 3;                 // 0..63
  const int bh = xcd * 4 + (j >> 4);
  const int qb = 15 - (j & 15);
  const int q0 = qb * 128;
  const int b = bh >> 4, h = bh & 15;
  const int qw0 = q0 + wave * 32;        // this wave's first q row

  const u16* Kg = Khp + (size_t)b * SEQ * DDIM + h * HD;
  const u16* Lg = Klp + (size_t)b * SEQ * DDIM + h * HD;
  const u16* Vg = Vt + (size_t)bh * HD * SEQ;

  // Q fragments (B-operand): B[k][col=q]: lane holds q=lq, k=hi*8+e per 16-d slice
  bf16x8 qf[8];
#pragma unroll
  for (int ks = 0; ks < 8; ++ks)
    qf[ks] = *(const bf16x8*)&Qh[(size_t)(b * SEQ + qw0 + lq) * DDIM + h * HD + ks * 16 + hi * 8];

  // staging geometry (per lane)
  const int krow0 = wave * 4 + (lane >> 4);   // + it*16, K rows 256B
  const int kcolb = (lane & 15) << 4;
  const int vrow0 = wave * 8 + (lane >> 3);   // + it*32, V rows 128B
  const int vcolb = (lane & 7) << 4;

  auto STAGE = [&](int buf, int t) {
    const int kbase = t * 64;
#pragma unroll
    for (int it = 0; it < 4; ++it) {
      const int r = it * 16 + krow0;
      const int c = (kcolb ^ ((r & 7) << 4)) >> 1;
      const size_t g = (size_t)(kbase + r) * DDIM + c;
      gload16(Kg + g, &Ksh[buf][(it * 16 + wave * 4) * 128]);
      gload16(Lg + g, &Ksl[buf][(it * 16 + wave * 4) * 128]);
    }
#pragma unroll
    for (int it = 0; it < 4; ++it) {
      const int d = it * 32 + vrow0;
      const int c = (vcolb ^ ((d & 7) << 4)) >> 1;
      gload16(Vg + (size_t)d * SEQ + kbase + c, &Vs[buf][(it * 32 + wave * 8) * 64]);
    }
  };

  float m = NEG_INF, l = 0.f;
  f32x16 o[4] = {};   // o[db]: rows d = db*32+(r&3)+8*(r>>2)+4*hi, col q = lq

  const int nt = 2 * qb + 2;   // 64-key tiles covering keys 0 .. q0+127
  int cur = 0;
  STAGE(0, 0);
  __syncthreads();

  for (int t = 0; t < nt; ++t) {
    if (t + 1 < nt) STAGE(cur ^ 1, t + 1);
#pragma unroll
    for (int ks2 = 0; ks2 < 2; ++ks2) {
      const int k0 = t * 64 + ks2 * 32;
      if (k0 <= qw0 + 31) {              // wave-uniform skip of fully-masked subtiles
        // ---- QK^T swapped: s[key-rows][q-cols], 2 terms ----
        f32x16 s = {};
        __builtin_amdgcn_s_setprio(1);
#pragma unroll
        for (int d8 = 0; d8 < 8; ++d8) {
          const int krow = ks2 * 32 + lq;
          const int cb = ((d8 * 32 + hi * 16) ^ ((krow & 7) << 4)) >> 1;
          bf16x8 kfh = *(const bf16x8*)&Ksh[cur][krow * 128 + cb];
          s = __builtin_amdgcn_mfma_f32_32x32x16_bf16(kfh, qf[d8], s, 0, 0, 0);
          bf16x8 kfl = *(const bf16x8*)&Ksl[cur][krow * 128 + cb];
          s = __builtin_amdgcn_mfma_f32_32x32x16_bf16(kfl, qf[d8], s, 0, 0, 0);
        }
        __builtin_amdgcn_s_setprio(0);
        // ---- causal mask (rows = keys, per-lane col q) ----
        if (k0 + 31 > qw0) {
          const int qrow = qw0 + lq;
#pragma unroll
          for (int r = 0; r < 16; ++r) {
            const int key = k0 + (r & 3) + 8 * (r >> 2) + 4 * hi;
            if (key > qrow) s[r] = NEG_INF;
          }
        }
        // ---- row max: in-lane tree + one cross-half shfl ----
        float rm = s[0];
#pragma unroll
        for (int r = 1; r < 16; ++r) rm = fmaxf(rm, s[r]);
        rm = fmaxf(rm, __shfl_xor(rm, 32));
        // ---- defer-max (THR=8) ----
        if (!__all(rm - m <= 8.0f)) {
          const float mn = fmaxf(m, rm);
          const float al = __expf(m - mn);
#pragma unroll
          for (int db = 0; db < 4; ++db)
#pragma unroll
            for (int r = 0; r < 16; ++r) o[db][r] *= al;
          l *= al;
          m = mn;
        }
        // ---- p = exp(s-m), row-sum, pack to bf16 pairs ----
        float ps[16];
        float ls = 0.f;
#pragma unroll
        for (int r = 0; r < 16; ++r) { ps[r] = __expf(s[r] - m); ls += ps[r]; }
        l += ls + __shfl_xor(ls, 32);
        unsigned pk[8], sw[8];
#pragma unroll
        for (int jj = 0; jj < 8; ++jj) {
          pk[jj] = (unsigned)f2bf(ps[2 * jj]) | ((unsigned)f2bf(ps[2 * jj + 1]) << 16);
          sw[jj] = __shfl_xor(pk[jj], 32);
        }
        // ---- PV swapped: o[d-rows][q-cols] += mfma(Vt_frag, P_frag) ----
        __builtin_amdgcn_s_setprio(1);
#pragma unroll
        for (int ksl = 0; ksl < 2; ++ksl) {
          union { unsigned u[4]; bf16x8 v; } pb;
          pb.u[0] = hi ? sw[4 * ksl + 2] : pk[4 * ksl + 0];
          pb.u[1] = hi ? sw[4 * ksl + 3] : pk[4 * ksl + 1];
          pb.u[2] = hi ? pk[4 * ksl + 2] : sw[4 * ksl + 0];
          pb.u[3] = hi ? pk[4 * ksl + 3] : sw[4 * ksl + 1];
#pragma unroll
          for (int db = 0; db < 4; ++db) {
            const int d = db * 32 + lq;
            const int cb = ((ks2 * 64 + ksl * 32 + hi * 16) ^ ((d & 7) << 4)) >> 1;
            bf16x8 vf = *(const bf16x8*)&Vs[cur][d * 64 + cb];
            o[db] = __builtin_amdgcn_mfma_f32_32x32x16_bf16(vf, pb.v, o[db], 0, 0, 0);
          }
        }
        __builtin_amdgcn_s_setprio(0);
      }
    }
    __syncthreads();   // drains prefetch vmcnt + protects LDS buffer reuse
    cur ^= 1;
  }

  // ---- epilogue: o/l, transpose [d][q]->[q][d] through (dead) V LDS, b128 stores ----
  u16* sm = (u16*)&Vs[0][0] + wave * 4096;   // 8 KB per wave (32 rows x 256B, swz (q&7)<<4)
#pragma unroll
  for (int db = 0; db < 4; ++db)
#pragma unroll
    for (int jj = 0; jj < 8; ++jj) {
      const int d0 = db * 32 + 8 * (jj >> 1) + 4 * hi + 2 * (jj & 1);
      const unsigned w = (unsigned)f2bf(o[db][2 * jj] / l) |
                         ((unsigned)f2bf(o[db][2 * jj + 1] / l) << 16);
      *(unsigned*)&sm[((lq * 256 + d0 * 2) ^ ((lq & 7) << 4)) >> 1] = w;
    }
  __builtin_amdgcn_wave_barrier();
  {
    const int qr = lane >> 1, hb = lane & 1;
    const size_t rowbase = (size_t)(b * SEQ + qw0 + qr) * DDIM + h * HD + hb * 64;
#pragma unroll
    for (int c = 0; c < 8; ++c) {
      const int byte = (qr * 256 + hb * 128 + c * 16) ^ ((qr & 7) << 4);
      bf16x8 vv = *(const bf16x8*)&sm[byte >> 1];
      *(bf16x8*)&ctx[rowbase + c * 8] = vv;
    }
  }
}

// ---------------- launch ----------------
extern "C" void kernel_launch(void* const* d_in, const int* in_sizes, int n_in,
                              void* d_out, int out_size, void* d_ws, size_t ws_size,
                              hipStream_t stream) {
  const float* X  = (const float*)d_in[0];
  const float* Wq = (const float*)d_in[1];
  const float* Wk = (const float*)d_in[2];
  const float* Wv = (const float*)d_in[3];
  const float* Wo = (const float*)d_in[4];
  const float* bo = (const float*)d_in[5];
  float* out = (float*)d_out;

  const size_t SZ_XD = (size_t)MROWS * DDIM * 2;  // 16 MiB
  const size_t SZ_W  = (size_t)DDIM * DDIM * 2;   // 8 MiB

  char* p = (char*)d_ws;
  auto alloc = [&](size_t bytes) {
    char* r = p;
    p += (bytes + 255) & ~(size_t)255;
    return r;
  };
  u16* Xh  = (u16*)alloc(SZ_XD);
  u16* Xl  = (u16*)alloc(SZ_XD);
  u16* Wbh = (u16*)alloc(SZ_W);   // W staging region, reused per weight
  u16* Wbl = (u16*)alloc(SZ_W);
  u16* Qh  = (u16*)alloc(SZ_XD);
  u16* Kh  = (u16*)alloc(SZ_XD);
  u16* Kl  = (u16*)alloc(SZ_XD);
  u16* Vb  = (u16*)alloc(SZ_XD);
  u16* Vt  = Xh;   // Xh dead after V projection
  u16* ctx = Qh;   // each attn block reads exactly the Q panel it overwrites

  split_x<<<(MROWS * DDIM) / 1024, 256, 0, stream>>>(X, Xh, Xl);

  dim3 tb(32, 8);
  dim3 gg(DDIM / 128, MROWS / 128);

  transpose_w<<<dim3(64, 64), tb, 0, stream>>>(Wq, Wbh, Wbl);
  gemm3_kernel<2, false><<<gg, 256, 0, stream>>>(Xh, Xl, Wbh, Wbl, Qh, nullptr);

  transpose_w<<<dim3(64, 64), tb, 0, stream>>>(Wk, Wbh, Wbl);
  gemm3_kernel<3, true><<<gg, 256, 0, stream>>>(Xh, Xl, Wbh, Wbl, Kh, Kl);

  transpose_w<<<dim3(64, 64), tb, 0, stream>>>(Wv, Wbh, nullptr);
  gemm_kernel<0><<<gg, 256, 0, stream>>>(Xh, Wbh, Vb, nullptr);

  transpose_v<<<dim3(SEQ / 32, HD / 32, BATCH * NH), tb, 0, stream>>>(Vb, Vt);

  transpose_w<<<dim3(64, 64), tb, 0, stream>>>(Wo, Wbh, nullptr);

  attn_kernel<<<512, 256, 0, stream>>>(Qh, Kh, Kl, Vt, ctx);

  gemm_kernel<2><<<gg, 256, 0, stream>>>(ctx, Wbh, out, bo);
}

// Round 7
// 537.938 us; speedup vs baseline: 1.1108x; 1.1108x over previous
//
#include <hip/hip_runtime.h>
#include <hip/hip_bf16.h>
#include <math.h>

// ---------------- problem constants ----------------
#define BATCH 2
#define SEQ   2048
#define DDIM  2048
#define NH    16
#define HD    128
#define MROWS (BATCH * SEQ)   // 4096

typedef unsigned short u16;
typedef __bf16 bf16x8 __attribute__((ext_vector_type(8)));
typedef float  f32x4  __attribute__((ext_vector_type(4)));
typedef float  f32x16 __attribute__((ext_vector_type(16)));

// round-to-nearest-even f32 -> bf16 bits
__device__ __forceinline__ u16 f2bf(float f) {
  unsigned int u = __float_as_uint(f);
  u += 0x7fffu + ((u >> 16) & 1u);
  return (u16)(u >> 16);
}
__device__ __forceinline__ float bf2f(u16 h) {
  return __uint_as_float(((unsigned int)h) << 16);
}

// async global->LDS, 16B per lane; LDS dest is wave-uniform base + lane*16
__device__ __forceinline__ void gload16(const void* g, void* s) {
  __builtin_amdgcn_global_load_lds((const __attribute__((address_space(1))) void*)g,
                                   (__attribute__((address_space(3))) void*)s, 16, 0, 0);
}

// ---------------- X f32 -> (hi, lo) bf16 pair ----------------
__global__ void split_x(const float* __restrict__ in, u16* __restrict__ hi,
                        u16* __restrict__ lo) {
  const int i = blockIdx.x * blockDim.x + threadIdx.x;   // one float4 per thread
  float4 v = ((const float4*)in)[i];
  ushort4 h, l;
  h.x = f2bf(v.x); l.x = f2bf(v.x - bf2f(h.x));
  h.y = f2bf(v.y); l.y = f2bf(v.y - bf2f(h.y));
  h.z = f2bf(v.z); l.z = f2bf(v.z - bf2f(h.z));
  h.w = f2bf(v.w); l.w = f2bf(v.w - bf2f(h.w));
  ((ushort4*)hi)[i] = h;
  ((ushort4*)lo)[i] = l;
}

// ---------------- W [K][N] f32 -> Wt [N][K] bf16 (hi [+ lo]) ----------------
__global__ void transpose_w(const float* __restrict__ W, u16* __restrict__ Wth,
                            u16* __restrict__ Wtl) {
  __shared__ float t[32][33];
  const int tx = threadIdx.x, ty = threadIdx.y;          // 32 x 8
  const int c0 = blockIdx.x * 32, r0 = blockIdx.y * 32;  // c0: n, r0: k
#pragma unroll
  for (int i = 0; i < 4; ++i)
    t[ty + i * 8][tx] = W[(size_t)(r0 + ty + i * 8) * DDIM + c0 + tx];
  __syncthreads();
#pragma unroll
  for (int i = 0; i < 4; ++i) {
    const float v = t[tx][ty + i * 8];
    const u16 h = f2bf(v);
    const size_t idx = (size_t)(c0 + ty + i * 8) * DDIM + r0 + tx;
    Wth[idx] = h;
    if (Wtl) Wtl[idx] = f2bf(v - bf2f(h));
  }
}

// ---------------- V [B*S][D] bf16 -> Vt [B*H][HD][S] bf16 ----------------
__global__ void transpose_v(const u16* __restrict__ V, u16* __restrict__ Vt) {
  __shared__ u16 t[32][33];
  const int tx = threadIdx.x, ty = threadIdx.y;          // 32 x 8
  const int s0 = blockIdx.x * 32;
  const int d0 = blockIdx.y * 32;
  const int bh = blockIdx.z;
  const int b = bh >> 4, h = bh & 15;
#pragma unroll
  for (int i = 0; i < 4; ++i)
    t[ty + i * 8][tx] = V[(size_t)(b * SEQ + s0 + ty + i * 8) * DDIM + h * HD + d0 + tx];
  __syncthreads();
#pragma unroll
  for (int i = 0; i < 4; ++i)
    Vt[((size_t)bh * HD + d0 + ty + i * 8) * SEQ + s0 + tx] = t[tx][ty + i * 8];
}

// XCD-aware block swizzle for the 16x32 GEMM grids (512 wgs, 512%8==0).
// Each XCD gets one 8x8-tile supertile (1024x1024 C region) -> L2 panel reuse.
__device__ __forceinline__ void gemm_tile_swz(int& bm, int& bn) {
  const int idb = blockIdx.y * 16 + blockIdx.x;
  const int xcd = idb & 7, jj = idb >> 3;
  bn = (((xcd & 1) << 3) + (jj >> 3)) * 128;
  bm = (((xcd >> 1) << 3) + (jj & 7)) * 128;
}

// ---------------- single-term GEMM: C[M,N] = A[M,K] x Bt[N,K]^T ----------------
template <int MODE>
__global__ __launch_bounds__(256)
void gemm_kernel(const u16* __restrict__ A, const u16* __restrict__ Bt,
                 void* __restrict__ Cout, const float* __restrict__ bias) {
  constexpr int K = DDIM, N = DDIM;
  __shared__ __align__(16) u16 As[128 * 64];
  __shared__ __align__(16) u16 Bs[128 * 64];
  const int tid = threadIdx.x;
  const int wave = tid >> 6;
  const int lane = tid & 63;
  const int lr = lane & 15, lg = lane >> 4;
  int bm, bn;
  gemm_tile_swz(bm, bn);
  const int wr = wave >> 1, wc = wave & 1;

  f32x4 acc[4][4] = {};

  const int srow = wave * 32 + (lane >> 3);
  const int scol = (lane & 7) * 8;
  const u16* Ag = A  + (size_t)(bm + srow) * K + scol;
  const u16* Bg = Bt + (size_t)(bn + srow) * K + scol;

  for (int k0 = 0; k0 < K; k0 += 64) {
    __syncthreads();
#pragma unroll
    for (int it = 0; it < 4; ++it) {
      gload16(Ag + (size_t)it * 8 * K + k0, &As[(wave * 32 + it * 8) * 64]);
      gload16(Bg + (size_t)it * 8 * K + k0, &Bs[(wave * 32 + it * 8) * 64]);
    }
    __syncthreads();
#pragma unroll
    for (int kk = 0; kk < 64; kk += 32) {
      bf16x8 af[4], bfr[4];
#pragma unroll
      for (int i = 0; i < 4; ++i)
        af[i] = *(const bf16x8*)&As[(wr * 64 + i * 16 + lr) * 64 + kk + lg * 8];
#pragma unroll
      for (int j = 0; j < 4; ++j)
        bfr[j] = *(const bf16x8*)&Bs[(wc * 64 + j * 16 + lr) * 64 + kk + lg * 8];
#pragma unroll
      for (int i = 0; i < 4; ++i)
#pragma unroll
        for (int j = 0; j < 4; ++j)
          acc[i][j] = __builtin_amdgcn_mfma_f32_16x16x32_bf16(af[i], bfr[j], acc[i][j], 0, 0, 0);
    }
  }

#pragma unroll
  for (int i = 0; i < 4; ++i) {
    const int row0 = bm + wr * 64 + i * 16 + lg * 4;
#pragma unroll
    for (int j = 0; j < 4; ++j) {
      const int col = bn + wc * 64 + j * 16 + lr;
#pragma unroll
      for (int e = 0; e < 4; ++e) {
        const int row = row0 + e;
        const float v = acc[i][j][e];
        if constexpr (MODE == 0) {
          ((u16*)Cout)[(size_t)row * N + col] = f2bf(v);
        } else {
          ((float*)Cout)[(size_t)row * N + col] = v + bias[col];
        }
      }
    }
  }
}

// ------- split GEMM: C = A x (Bh+Bl)^T (+ Al x Bh^T if TERMS==3) -------
template <int TERMS, bool WRITE_LO>
__global__ __launch_bounds__(256)
void gemm3_kernel(const u16* __restrict__ Ah, const u16* __restrict__ Al,
                  const u16* __restrict__ Bh, const u16* __restrict__ Bl,
                  u16* __restrict__ Ch, u16* __restrict__ Cl) {
  constexpr int K = DDIM, N = DDIM;
  __shared__ __align__(16) u16 Ash[128 * 64];
  __shared__ __align__(16) u16 Asl[TERMS == 3 ? 128 * 64 : 8];
  __shared__ __align__(16) u16 Bsh[128 * 64];
  __shared__ __align__(16) u16 Bsl[128 * 64];
  const int tid = threadIdx.x;
  const int wave = tid >> 6;
  const int lane = tid & 63;
  const int lr = lane & 15, lg = lane >> 4;
  int bm, bn;
  gemm_tile_swz(bm, bn);
  const int wr = wave >> 1, wc = wave & 1;

  f32x4 acc[4][4] = {};

  const int srow = wave * 32 + (lane >> 3);
  const int scol = (lane & 7) * 8;
  const size_t aoff = (size_t)(bm + srow) * K + scol;
  const size_t boff = (size_t)(bn + srow) * K + scol;

  for (int k0 = 0; k0 < K; k0 += 64) {
    __syncthreads();
#pragma unroll
    for (int it = 0; it < 4; ++it) {
      const size_t ro = (size_t)it * 8 * K + k0;
      const int ls = (wave * 32 + it * 8) * 64;
      gload16(Ah + aoff + ro, &Ash[ls]);
      if constexpr (TERMS == 3) gload16(Al + aoff + ro, &Asl[ls]);
      gload16(Bh + boff + ro, &Bsh[ls]);
      gload16(Bl + boff + ro, &Bsl[ls]);
    }
    __syncthreads();
#pragma unroll
    for (int kk = 0; kk < 64; kk += 32) {
      bf16x8 ah[4], al[4], bh[4], bl[4];
#pragma unroll
      for (int i = 0; i < 4; ++i) {
        const int off = (wr * 64 + i * 16 + lr) * 64 + kk + lg * 8;
        ah[i] = *(const bf16x8*)&Ash[off];
        if constexpr (TERMS == 3) al[i] = *(const bf16x8*)&Asl[off];
      }
#pragma unroll
      for (int j = 0; j < 4; ++j) {
        const int off = (wc * 64 + j * 16 + lr) * 64 + kk + lg * 8;
        bh[j] = *(const bf16x8*)&Bsh[off];
        bl[j] = *(const bf16x8*)&Bsl[off];
      }
#pragma unroll
      for (int i = 0; i < 4; ++i)
#pragma unroll
        for (int j = 0; j < 4; ++j) {
          acc[i][j] = __builtin_amdgcn_mfma_f32_16x16x32_bf16(ah[i], bh[j], acc[i][j], 0, 0, 0);
          acc[i][j] = __builtin_amdgcn_mfma_f32_16x16x32_bf16(ah[i], bl[j], acc[i][j], 0, 0, 0);
          if constexpr (TERMS == 3)
            acc[i][j] = __builtin_amdgcn_mfma_f32_16x16x32_bf16(al[i], bh[j], acc[i][j], 0, 0, 0);
        }
    }
  }

#pragma unroll
  for (int i = 0; i < 4; ++i) {
    const int row0 = bm + wr * 64 + i * 16 + lg * 4;
#pragma unroll
    for (int j = 0; j < 4; ++j) {
      const int col = bn + wc * 64 + j * 16 + lr;
#pragma unroll
      for (int e = 0; e < 4; ++e) {
        const float v = acc[i][j][e];
        const u16 h = f2bf(v);
        const size_t idx = (size_t)(row0 + e) * N + col;
        Ch[idx] = h;
        if constexpr (WRITE_LO) Cl[idx] = f2bf(v - bf2f(h));
      }
    }
  }
}

// ---------------- causal flash attention v5: counted-vmcnt pipeline ----------------
// 512 blocks x 256 threads (4 waves x 32 q-rows). LDS 80KB -> 2 blocks/CU.
// Per 64-key tile: stage V(t) + K(t+1) (async), s_waitcnt vmcnt(12) + barrier
// (K(t) ready, K(t+1) stays IN FLIGHT), QK subtile0, vmcnt(8)+barrier (V ready),
// PV0, QK1, PV1, barrier. No full drain in the main loop (T4).
__global__ __launch_bounds__(256, 2)
void attn_kernel(const u16* __restrict__ Qh, const u16* __restrict__ Khp,
                 const u16* __restrict__ Klp, const u16* __restrict__ Vt,
                 u16* __restrict__ ctx) {
  __shared__ __align__(16) u16 Ksh[2][64 * 128];   // [key][d] rows 256B, swz (r&7)<<4
  __shared__ __align__(16) u16 Ksl[2][64 * 128];
  __shared__ __align__(16) u16 Vs[128 * 64];       // [d][key] rows 128B, swz (d&7)<<4
  const int tid = threadIdx.x;
  const int wave = tid >> 6, lane = tid & 63;
  const int lq = lane & 31;
  const int hi = lane >> 5;
  const float NEG_INF = -__builtin_inff();

  // per-XCD queue: 4 heads x qb 15..0 (descending = longest first)
  const int id = blockIdx.x;
  const int xcd = id & 7;
  const int j = id >> 3;
  const int bh = xcd * 4 + (j >> 4);
  const int qb = 15 - (j & 15);
  const int q0 = qb * 128;
  const int b = bh >> 4, h = bh & 15;
  const int qw0 = q0 + wave * 32;

  const u16* Kg = Khp + (size_t)b * SEQ * DDIM + h * HD;
  const u16* Lg = Klp + (size_t)b * SEQ * DDIM + h * HD;
  const u16* Vg = Vt + (size_t)bh * HD * SEQ;

  // staging geometry (lane-const; swizzle row-bits are it-invariant)
  const int krow0 = wave * 4 + (lane >> 4);
  const int kc = (((lane & 15) << 4) ^ ((krow0 & 7) << 4)) >> 1;
  const int vrow0 = wave * 8 + (lane >> 3);
  const int vc = (((lane & 7) << 4) ^ ((vrow0 & 7) << 4)) >> 1;
  size_t koff[4], voff[4];
#pragma unroll
  for (int it = 0; it < 4; ++it) {
    koff[it] = (size_t)(it * 16 + krow0) * DDIM + kc;
    voff[it] = (size_t)(it * 32 + vrow0) * SEQ + vc;
  }

  auto STAGE_K = [&](int buf, int t) {   // 8 loads/lane
    const size_t tb = (size_t)t * 64 * DDIM;
#pragma unroll
    for (int it = 0; it < 4; ++it) {
      gload16(Kg + tb + koff[it], &Ksh[buf][(it * 16 + wave * 4) * 128]);
      gload16(Lg + tb + koff[it], &Ksl[buf][(it * 16 + wave * 4) * 128]);
    }
  };
  auto STAGE_V = [&](int t) {            // 4 loads/lane, single buffer
    const size_t tb = (size_t)t * 64;
#pragma unroll
    for (int it = 0; it < 4; ++it)
      gload16(Vg + tb + voff[it], &Vs[(it * 32 + wave * 8) * 64]);
  };

  STAGE_K(0, 0);
  // Q fragments (B-operand): lane holds q=lq, k=hi*8+e per 16-d slice
  bf16x8 qf[8];
#pragma unroll
  for (int ks = 0; ks < 8; ++ks)
    qf[ks] = *(const bf16x8*)&Qh[(size_t)(b * SEQ + qw0 + lq) * DDIM + h * HD + ks * 16 + hi * 8];

  float m = NEG_INF, l = 0.f;
  f32x16 o[4] = {};   // o[db]: rows d = db*32+(r&3)+8*(r>>2)+4*hi, col q = lq

  const int nt = 2 * qb + 2;
  int cur = 0;

  for (int t = 0; t < nt; ++t) {
    STAGE_V(t);
    const bool more = (t + 1 < nt);
    if (more) {
      STAGE_K(cur ^ 1, t + 1);
      asm volatile("s_waitcnt vmcnt(12)" ::: "memory");  // K(t) landed; V(t)+K(t+1) in flight
    } else {
      asm volatile("s_waitcnt vmcnt(4)" ::: "memory");   // K(t) landed; V(t) in flight
    }
    __builtin_amdgcn_s_barrier();
    __builtin_amdgcn_sched_barrier(0);

#pragma unroll
    for (int ks2 = 0; ks2 < 2; ++ks2) {
      const int k0 = t * 64 + ks2 * 32;
      const bool act = (k0 <= qw0 + 31);   // wave-uniform
      unsigned pk[8];
      if (act) {
        // ---- QK^T swapped, 2 independent 8-deep chains (Kh, Kl) ----
        f32x16 s1 = {}, s2 = {};
        const int krow = ks2 * 32 + lq;
        const int swz = (krow & 7) << 4;
        __builtin_amdgcn_s_setprio(1);
#pragma unroll
        for (int d8 = 0; d8 < 8; ++d8) {
          const int cb = ((d8 * 32 + hi * 16) ^ swz) >> 1;
          bf16x8 kfh = *(const bf16x8*)&Ksh[cur][krow * 128 + cb];
          s1 = __builtin_amdgcn_mfma_f32_32x32x16_bf16(kfh, qf[d8], s1, 0, 0, 0);
          bf16x8 kfl = *(const bf16x8*)&Ksl[cur][krow * 128 + cb];
          s2 = __builtin_amdgcn_mfma_f32_32x32x16_bf16(kfl, qf[d8], s2, 0, 0, 0);
        }
        __builtin_amdgcn_s_setprio(0);
        f32x16 s = s1 + s2;
        // ---- causal mask (rows = keys, per-lane col q) ----
        if (k0 + 31 > qw0) {
          const int qrow = qw0 + lq;
#pragma unroll
          for (int r = 0; r < 16; ++r) {
            const int key = k0 + (r & 3) + 8 * (r >> 2) + 4 * hi;
            if (key > qrow) s[r] = NEG_INF;
          }
        }
        // ---- row max: in-lane tree + one cross-half shfl ----
        float rm = s[0];
#pragma unroll
        for (int r = 1; r < 16; ++r) rm = fmaxf(rm, s[r]);
        rm = fmaxf(rm, __shfl_xor(rm, 32));
        // ---- defer-max (THR=8) ----
        if (!__all(rm - m <= 8.0f)) {
          const float mn = fmaxf(m, rm);
          const float al = __expf(m - mn);
#pragma unroll
          for (int db = 0; db < 4; ++db)
#pragma unroll
            for (int r = 0; r < 16; ++r) o[db][r] *= al;
          l *= al;
          m = mn;
        }
        // ---- p = exp(s-m), row-sum, pack to bf16 pairs ----
        float ps[16];
        float ls = 0.f;
#pragma unroll
        for (int r = 0; r < 16; ++r) { ps[r] = __expf(s[r] - m); ls += ps[r]; }
        l += ls + __shfl_xor(ls, 32);
#pragma unroll
        for (int jj = 0; jj < 8; ++jj)
          pk[jj] = (unsigned)f2bf(ps[2 * jj]) | ((unsigned)f2bf(ps[2 * jj + 1]) << 16);
      }
      if (ks2 == 0) {   // V(t) ready before first PV; K(t+1) stays in flight
        if (more) asm volatile("s_waitcnt vmcnt(8)" ::: "memory");
        else      asm volatile("s_waitcnt vmcnt(0)" ::: "memory");
        __builtin_amdgcn_s_barrier();
        __builtin_amdgcn_sched_barrier(0);
      }
      if (act) {
        unsigned sw[8];
#pragma unroll
        for (int jj = 0; jj < 8; ++jj) sw[jj] = __shfl_xor(pk[jj], 32);
        // ---- PV swapped: o[d-rows][q-cols] += mfma(Vt_frag, P_frag) ----
        __builtin_amdgcn_s_setprio(1);
#pragma unroll
        for (int ksl = 0; ksl < 2; ++ksl) {
          union { unsigned u[4]; bf16x8 v; } pb;
          pb.u[0] = hi ? sw[4 * ksl + 2] : pk[4 * ksl + 0];
          pb.u[1] = hi ? sw[4 * ksl + 3] : pk[4 * ksl + 1];
          pb.u[2] = hi ? pk[4 * ksl + 2] : sw[4 * ksl + 0];
          pb.u[3] = hi ? pk[4 * ksl + 3] : sw[4 * ksl + 1];
#pragma unroll
          for (int db = 0; db < 4; ++db) {
            const int d = db * 32 + lq;
            const int cb = ((ks2 * 64 + ksl * 32 + hi * 16) ^ ((d & 7) << 4)) >> 1;
            bf16x8 vf = *(const bf16x8*)&Vs[d * 64 + cb];
            o[db] = __builtin_amdgcn_mfma_f32_32x32x16_bf16(vf, pb.v, o[db], 0, 0, 0);
          }
        }
        __builtin_amdgcn_s_setprio(0);
      }
    }
    __builtin_amdgcn_s_barrier();   // all reads of Vs / Ksh[cur] done
    __builtin_amdgcn_sched_barrier(0);
    cur ^= 1;
  }

  // ---- epilogue: o/l, transpose [d][q]->[q][d] through dead Ksh LDS ----
  u16* sm = (u16*)Ksh + wave * 4096;   // 8 KB per wave (32 rows x 256B, swz (q&7)<<4)
#pragma unroll
  for (int db = 0; db < 4; ++db)
#pragma unroll
    for (int jj = 0; jj < 8; ++jj) {
      const int d0 = db * 32 + 8 * (jj >> 1) + 4 * hi + 2 * (jj & 1);
      const unsigned w = (unsigned)f2bf(o[db][2 * jj] / l) |
                         ((unsigned)f2bf(o[db][2 * jj + 1] / l) << 16);
      *(unsigned*)&sm[((lq * 256 + d0 * 2) ^ ((lq & 7) << 4)) >> 1] = w;
    }
  __builtin_amdgcn_wave_barrier();
  {
    const int qr = lane >> 1, hb = lane & 1;
    const size_t rowbase = (size_t)(b * SEQ + qw0 + qr) * DDIM + h * HD + hb * 64;
#pragma unroll
    for (int c = 0; c < 8; ++c) {
      const int byte = (qr * 256 + hb * 128 + c * 16) ^ ((qr & 7) << 4);
      bf16x8 vv = *(const bf16x8*)&sm[byte >> 1];
      *(bf16x8*)&ctx[rowbase + c * 8] = vv;
    }
  }
}

// ---------------- launch ----------------
extern "C" void kernel_launch(void* const* d_in, const int* in_sizes, int n_in,
                              void* d_out, int out_size, void* d_ws, size_t ws_size,
                              hipStream_t stream) {
  const float* X  = (const float*)d_in[0];
  const float* Wq = (const float*)d_in[1];
  const float* Wk = (const float*)d_in[2];
  const float* Wv = (const float*)d_in[3];
  const float* Wo = (const float*)d_in[4];
  const float* bo = (const float*)d_in[5];
  float* out = (float*)d_out;

  const size_t SZ_XD = (size_t)MROWS * DDIM * 2;  // 16 MiB
  const size_t SZ_W  = (size_t)DDIM * DDIM * 2;   // 8 MiB

  char* p = (char*)d_ws;
  auto alloc = [&](size_t bytes) {
    char* r = p;
    p += (bytes + 255) & ~(size_t)255;
    return r;
  };
  u16* Xh  = (u16*)alloc(SZ_XD);
  u16* Xl  = (u16*)alloc(SZ_XD);
  u16* Wbh = (u16*)alloc(SZ_W);   // W staging region, reused per weight
  u16* Wbl = (u16*)alloc(SZ_W);
  u16* Qh  = (u16*)alloc(SZ_XD);
  u16* Kh  = (u16*)alloc(SZ_XD);
  u16* Kl  = (u16*)alloc(SZ_XD);
  u16* Vb  = (u16*)alloc(SZ_XD);
  u16* Vt  = Xh;   // Xh dead after V projection
  u16* ctx = Qh;   // each attn block reads exactly the Q panel it overwrites

  split_x<<<(MROWS * DDIM) / 1024, 256, 0, stream>>>(X, Xh, Xl);

  dim3 tb(32, 8);
  dim3 gg(DDIM / 128, MROWS / 128);

  transpose_w<<<dim3(64, 64), tb, 0, stream>>>(Wq, Wbh, Wbl);
  gemm3_kernel<2, false><<<gg, 256, 0, stream>>>(Xh, Xl, Wbh, Wbl, Qh, nullptr);

  transpose_w<<<dim3(64, 64), tb, 0, stream>>>(Wk, Wbh, Wbl);
  gemm3_kernel<3, true><<<gg, 256, 0, stream>>>(Xh, Xl, Wbh, Wbl, Kh, Kl);

  transpose_w<<<dim3(64, 64), tb, 0, stream>>>(Wv, Wbh, nullptr);
  gemm_kernel<0><<<gg, 256, 0, stream>>>(Xh, Wbh, Vb, nullptr);

  transpose_v<<<dim3(SEQ / 32, HD / 32, BATCH * NH), tb, 0, stream>>>(Vb, Vt);

  transpose_w<<<dim3(64, 64), tb, 0, stream>>>(Wo, Wbh, nullptr);

  attn_kernel<<<512, 256, 0, stream>>>(Qh, Kh, Kl, Vt, ctx);

  gemm_kernel<2><<<gg, 256, 0, stream>>>(ctx, Wbh, out, bo);
}